// Round 2
// baseline (259.340 us; speedup 1.0000x reference)
//
#include <hip/hip_runtime.h>
#include <math.h>

#define SIM_T 100
#define RB 4  // rows per block in k_encode -> 2048 blocks (8/CU)

// ---------------------------------------------------------------------------
// Kernel 0: permute W2 [256][256] -> W2p so each lane's 4 columns are one
// contiguous float4:  W2p[i*256 + l*4 + q] = W2[i*256 + 64*q + l]
// ---------------------------------------------------------------------------
__global__ __launch_bounds__(256) void k_perm(const float* __restrict__ W2,
                                              float* __restrict__ W2p) {
  int i = blockIdx.x;
  int t = threadIdx.x;
  int l = t >> 2, q = t & 3;
  W2p[i * 256 + t] = W2[i * 256 + q * 64 + l];
}

// ---------------------------------------------------------------------------
// Kernel 1: rates = sigmoid(x @ encW^T + b);  c = (rates @ W1) * (1-decay)
// 2048 blocks x 256 threads, 4 rows/block. Per-thread tile: 4 rows x 1 col
// (col = threadIdx.x). All LDS reads are wave-uniform broadcasts; weight
// loads are 16B-per-16FMA. Occupancy-first layout (R0 showed 11% occ was
// the bottleneck: 256 blocks = 1 wave/SIMD, latency-bound at VALUBusy 18%).
// ---------------------------------------------------------------------------
__global__ __launch_bounds__(256, 8) void k_encode(
    const float* __restrict__ x, const float* __restrict__ encW,
    const float* __restrict__ encB, const float* __restrict__ W1,
    float* __restrict__ c_out, float omd) {
  __shared__ float sh[RB * 256];  // 4 KB
  float4* sh4 = (float4*)sh;
  const int t = threadIdx.x;  // owned output column j = t
  const long rowbase = (long)blockIdx.x * RB;

  // stage x tile: 4 rows x 64 float4 = 256 float4, one per thread (coalesced)
  {
    const float4* xg = (const float4*)(x + rowbase * 256);
    sh4[t] = xg[t];
  }
  __syncthreads();

  float acc[4];
#pragma unroll
  for (int r = 0; r < 4; r++) acc[r] = 0.f;

  // phase A: acc[r] = sum_k x[r][k] * encW[t][k]   (encW is [out,in])
  for (int kt = 0; kt < 64; kt++) {
    float4 xv[4];
#pragma unroll
    for (int r = 0; r < 4; r++) xv[r] = sh4[r * 64 + kt];  // wave broadcast
    float4 w = *(const float4*)(encW + t * 256 + kt * 4);
    const float* xvf = &xv[0].x;
#pragma unroll
    for (int r = 0; r < 4; r++) {
      float a = acc[r];
      a = fmaf(xvf[r * 4 + 0], w.x, a);
      a = fmaf(xvf[r * 4 + 1], w.y, a);
      a = fmaf(xvf[r * 4 + 2], w.z, a);
      a = fmaf(xvf[r * 4 + 3], w.w, a);
      acc[r] = a;
    }
  }
  __syncthreads();
  // rates = sigmoid(acc + b) -> LDS (stride-4B store, conflict-free)
  {
    float b = encB[t];
#pragma unroll
    for (int r = 0; r < 4; r++) {
      float v = acc[r] + b;
      sh[r * 256 + t] = 1.f / (1.f + expf(-v));
    }
  }
  __syncthreads();

  // phase B: c[r][t] = (sum_k rates[r][k] * W1[k][t]) * omd
#pragma unroll
  for (int r = 0; r < 4; r++) acc[r] = 0.f;
  for (int kt = 0; kt < 64; kt++) {
    float4 rv[4];
#pragma unroll
    for (int r = 0; r < 4; r++) rv[r] = sh4[r * 64 + kt];  // wave broadcast
    const float* rvf = &rv[0].x;
#pragma unroll
    for (int kk = 0; kk < 4; kk++) {
      float w = W1[(kt * 4 + kk) * 256 + t];  // coalesced 256B/instr
#pragma unroll
      for (int r = 0; r < 4; r++) acc[r] = fmaf(rvf[r * 4 + kk], w, acc[r]);
    }
  }
#pragma unroll
  for (int r = 0; r < 4; r++)
    c_out[(rowbase + r) * 256 + t] = __fmul_rn(acc[r], omd);
}

// ---------------------------------------------------------------------------
// Kernel 2: the 100-step LIF simulation. One wave == one batch row.
// Lane l owns columns {l, 64+l, 128+l, 192+l} of layers 1/2 and column l of
// layer 3. Spike sets via __ballot -> uniform scalar ctz loops; per spike one
// coalesced float4 load of the permuted W2 row.
// ---------------------------------------------------------------------------
__global__ __launch_bounds__(256, 8) void k_sim(
    const float* __restrict__ c_in, const float* __restrict__ W2p,
    const float* __restrict__ W3, float* __restrict__ out, float decay,
    float omd) {
  const int lane = threadIdx.x & 63;
  const int row = blockIdx.x * 4 + (threadIdx.x >> 6);
  const float* crow = c_in + (long)row * 256;
  const float c0 = crow[lane];
  const float c1 = crow[64 + lane];
  const float c2 = crow[128 + lane];
  const float c3 = crow[192 + lane];
  float v10 = 0.f, v11 = 0.f, v12 = 0.f, v13 = 0.f;
  float v20 = 0.f, v21 = 0.f, v22 = 0.f, v23 = 0.f;
  float v3 = 0.f;
  int acc = 0;
  const float4* w2p = (const float4*)W2p + lane;  // w2p[i*64] = row i, 4 cols

  for (int t = 0; t < SIM_T; t++) {
    // ---- layer 1 (constant input c) ----
    v10 = __fadd_rn(__fmul_rn(v10, decay), c0);
    bool f0 = v10 >= 1.f;
    unsigned long long m0 = __ballot(f0);
    v10 = f0 ? 0.f : v10;
    v11 = __fadd_rn(__fmul_rn(v11, decay), c1);
    bool f1 = v11 >= 1.f;
    unsigned long long m1 = __ballot(f1);
    v11 = f1 ? 0.f : v11;
    v12 = __fadd_rn(__fmul_rn(v12, decay), c2);
    bool f2 = v12 >= 1.f;
    unsigned long long m2 = __ballot(f2);
    v12 = f2 ? 0.f : v12;
    v13 = __fadd_rn(__fmul_rn(v13, decay), c3);
    bool f3 = v13 >= 1.f;
    unsigned long long m3 = __ballot(f3);
    v13 = f3 ? 0.f : v13;

    // ---- layer 2: syn2 = sum of W2 rows of spiking layer-1 neurons ----
    float s0 = 0.f, s1 = 0.f, s2 = 0.f, s3 = 0.f;
#define ACC2(mask, qb)                            \
  {                                               \
    unsigned long long m = (mask);                \
    while (m) {                                   \
      int i = __builtin_ctzll(m) + (qb);          \
      m &= m - 1;                                 \
      float4 w = w2p[i * 64];                     \
      s0 += w.x;                                  \
      s1 += w.y;                                  \
      s2 += w.z;                                  \
      s3 += w.w;                                  \
    }                                             \
  }
    ACC2(m0, 0)
    ACC2(m1, 64)
    ACC2(m2, 128)
    ACC2(m3, 192)

    v20 = __fadd_rn(__fmul_rn(v20, decay), __fmul_rn(s0, omd));
    bool g0 = v20 >= 1.f;
    unsigned long long n0 = __ballot(g0);
    v20 = g0 ? 0.f : v20;
    v21 = __fadd_rn(__fmul_rn(v21, decay), __fmul_rn(s1, omd));
    bool g1 = v21 >= 1.f;
    unsigned long long n1 = __ballot(g1);
    v21 = g1 ? 0.f : v21;
    v22 = __fadd_rn(__fmul_rn(v22, decay), __fmul_rn(s2, omd));
    bool g2 = v22 >= 1.f;
    unsigned long long n2 = __ballot(g2);
    v22 = g2 ? 0.f : v22;
    v23 = __fadd_rn(__fmul_rn(v23, decay), __fmul_rn(s3, omd));
    bool g3 = v23 >= 1.f;
    unsigned long long n3 = __ballot(g3);
    v23 = g3 ? 0.f : v23;

    // ---- layer 3 (usually no layer-2 spikes: uniform skip) ----
    float z = 0.f;
    if (n0 | n1 | n2 | n3) {
#define ACC3(mask, qb)                            \
  {                                               \
    unsigned long long m = (mask);                \
    while (m) {                                   \
      int i = __builtin_ctzll(m) + (qb);          \
      m &= m - 1;                                 \
      z += W3[i * 64 + lane];                     \
    }                                             \
  }
      ACC3(n0, 0)
      ACC3(n1, 64)
      ACC3(n2, 128)
      ACC3(n3, 192)
    }
    v3 = __fadd_rn(__fmul_rn(v3, decay), __fmul_rn(z, omd));
    bool h = v3 >= 1.f;
    acc += h ? 1 : 0;
    v3 = h ? 0.f : v3;
  }
  out[(long)row * 64 + lane] = __fdiv_rn((float)acc, 100.f);
}

// ---------------------------------------------------------------------------
extern "C" void kernel_launch(void* const* d_in, const int* in_sizes, int n_in,
                              void* d_out, int out_size, void* d_ws,
                              size_t ws_size, hipStream_t stream) {
  const float* x = (const float*)d_in[0];     // [8192,256]
  const float* encW = (const float*)d_in[1];  // [256,256] (out,in)
  const float* encB = (const float*)d_in[2];  // [256]
  const float* W1 = (const float*)d_in[3];    // [256,256]
  const float* W2 = (const float*)d_in[4];    // [256,256]
  const float* W3 = (const float*)d_in[5];    // [256,64]
  float* out = (float*)d_out;                 // [8192,64]

  float* c = (float*)d_ws;                 // 8192*256 f32 = 8 MB
  float* W2p = (float*)d_ws + 8192 * 256;  // 256*256 f32 = 256 KB

  const float decay = (float)exp((double)(-0.05f));
  const float omd = 1.0f - decay;

  k_perm<<<256, 256, 0, stream>>>(W2, W2p);
  k_encode<<<2048, 256, 0, stream>>>(x, encW, encB, W1, c, omd);
  k_sim<<<2048, 256, 0, stream>>>(c, W2p, W3, out, decay, omd);
}

// Round 3
// 189.702 us; speedup vs baseline: 1.3671x; 1.3671x over previous
//
#include <hip/hip_runtime.h>
#include <math.h>

#define SIM_T 100

// ---------------------------------------------------------------------------
// Transpose encW [out][in] -> encWT [in][out] so GEMM weight reads are k-major.
// Coalesced writes; strided reads are L2-absorbed (256 KB total).
// ---------------------------------------------------------------------------
__global__ __launch_bounds__(256) void k_transpose256(
    const float* __restrict__ W, float* __restrict__ WT) {
  int k = blockIdx.x;
  int o = threadIdx.x;
  WT[k * 256 + o] = W[o * 256 + k];
}

// ---------------------------------------------------------------------------
// Permute W2 [256][256] -> W2p so each lane's 4 columns are one contiguous
// float4:  W2p[i*256 + l*4 + q] = W2[i*256 + 64*q + l]
// ---------------------------------------------------------------------------
__global__ __launch_bounds__(256) void k_perm(const float* __restrict__ W2,
                                              float* __restrict__ W2p) {
  int i = blockIdx.x;
  int t = threadIdx.x;
  int l = t >> 2, q = t & 3;
  W2p[i * 256 + t] = W2[i * 256 + q * 64 + l];
}

// ---------------------------------------------------------------------------
// GEMM: O[row][col] = epi( sum_k A[row][k] * WT[k][col] )
// Structure (R2 "S2"): lane = row, wave = 16-col slice -> WT reads are
// wave-uniform => scalar s_load (SMEM pipe, no LDS/vL1 cost), SGPR operand
// feeds v_fma directly. A-tile (64 rows x 1KB) lives in LDS with XOR swizzle
// (store sh4[row*64+(kt^row)], read sh4[lane*64+(kt^lane)]): conflict-free
// both ways. 512 blocks = 128 row-tiles x 4 col-splits; 2 blocks/CU (64KB
// LDS each), 2 waves/SIMD. Per kt: 1 ds_read_b128 + 4x16 uniform floats ->
// 64 FMAs. fmaf chain is k-ascending per output == R1's exact order.
// EPI 0: sigmoid(acc + bias)   EPI 1: acc * omd
// ---------------------------------------------------------------------------
template <int EPI>
__global__ __launch_bounds__(256, 2) void k_gemm64(
    const float* __restrict__ A,     // [8192][256]
    const float* __restrict__ WT,    // [256 k][256 col]
    const float* __restrict__ bias,  // encB (EPI=0) or unused
    float* __restrict__ O,           // [8192][256]
    float omd) {
  __shared__ float4 sh4[64 * 64];  // 64 KB
  float* shf = (float*)sh4;        // reused for output transpose (16 KB)
  const int t = threadIdx.x;
  const int lane = t & 63;
  const int w = t >> 6;
  const int rt = blockIdx.x >> 2;  // row tile (64 rows)
  const int cs = blockIdx.x & 3;   // col split (64 cols)
  const int colbase_v = cs * 64 + w * 16;
  const int colbase = __builtin_amdgcn_readfirstlane(colbase_v);

  // stage A-tile, swizzled; global reads fully coalesced
  {
    const float4* Ag = (const float4*)(A + (size_t)rt * 64 * 256);
#pragma unroll
    for (int i = 0; i < 16; i++) {
      int g = i * 256 + t;
      int row = g >> 6, kt = g & 63;
      sh4[row * 64 + (kt ^ row)] = Ag[g];
    }
  }
  __syncthreads();

  const float* wp = WT + colbase;  // wave-uniform
  float acc[16];
#pragma unroll
  for (int c = 0; c < 16; c++) acc[c] = 0.f;

  for (int kt = 0; kt < 64; kt++) {
    float4 xv = sh4[lane * 64 + (kt ^ lane)];
    const float* xf = &xv.x;
#pragma unroll
    for (int kk = 0; kk < 4; kk++) {
      const float* wk = wp + (kt * 4 + kk) * 256;  // uniform -> s_load
#pragma unroll
      for (int c = 0; c < 16; c++) acc[c] = fmaf(xf[kk], wk[c], acc[c]);
    }
  }
  __syncthreads();  // done with A-tile; reuse LDS for output transpose

  const int ccbase = (colbase_v & 63);  // w*16, in-block col base
  if (EPI == 0) {
#pragma unroll
    for (int c = 0; c < 16; c++) {
      float v = acc[c] + bias[colbase + c];
      float r = 1.f / (1.f + expf(-v));
      int cc = ccbase + c;
      shf[lane * 64 + (cc ^ lane)] = r;
    }
  } else {
#pragma unroll
    for (int c = 0; c < 16; c++) {
      int cc = ccbase + c;
      shf[lane * 64 + (cc ^ lane)] = __fmul_rn(acc[c], omd);
    }
  }
  __syncthreads();

  // coalesced store of the 64x64 output tile
  float* Obase = O + (size_t)rt * 64 * 256 + cs * 64;
#pragma unroll
  for (int i = 0; i < 16; i++) {
    int g = i * 256 + t;
    int row = g >> 6, cc = g & 63;
    Obase[row * 256 + cc] = shf[row * 64 + (cc ^ row)];
  }
}

// ---------------------------------------------------------------------------
// Kernel: the 100-step LIF simulation. One wave == one batch row.
// Lane l owns columns {l, 64+l, 128+l, 192+l} of layers 1/2 and column l of
// layer 3. Spike sets via __ballot -> uniform scalar ctz loops; per spike one
// coalesced float4 load of the permuted W2 row.  (unchanged from R1)
// ---------------------------------------------------------------------------
__global__ __launch_bounds__(256, 8) void k_sim(
    const float* __restrict__ c_in, const float* __restrict__ W2p,
    const float* __restrict__ W3, float* __restrict__ out, float decay,
    float omd) {
  const int lane = threadIdx.x & 63;
  const int row = blockIdx.x * 4 + (threadIdx.x >> 6);
  const float* crow = c_in + (long)row * 256;
  const float c0 = crow[lane];
  const float c1 = crow[64 + lane];
  const float c2 = crow[128 + lane];
  const float c3 = crow[192 + lane];
  float v10 = 0.f, v11 = 0.f, v12 = 0.f, v13 = 0.f;
  float v20 = 0.f, v21 = 0.f, v22 = 0.f, v23 = 0.f;
  float v3 = 0.f;
  int acc = 0;
  const float4* w2p = (const float4*)W2p + lane;  // w2p[i*64] = row i, 4 cols

  for (int t = 0; t < SIM_T; t++) {
    // ---- layer 1 (constant input c) ----
    v10 = __fadd_rn(__fmul_rn(v10, decay), c0);
    bool f0 = v10 >= 1.f;
    unsigned long long m0 = __ballot(f0);
    v10 = f0 ? 0.f : v10;
    v11 = __fadd_rn(__fmul_rn(v11, decay), c1);
    bool f1 = v11 >= 1.f;
    unsigned long long m1 = __ballot(f1);
    v11 = f1 ? 0.f : v11;
    v12 = __fadd_rn(__fmul_rn(v12, decay), c2);
    bool f2 = v12 >= 1.f;
    unsigned long long m2 = __ballot(f2);
    v12 = f2 ? 0.f : v12;
    v13 = __fadd_rn(__fmul_rn(v13, decay), c3);
    bool f3 = v13 >= 1.f;
    unsigned long long m3 = __ballot(f3);
    v13 = f3 ? 0.f : v13;

    // ---- layer 2: syn2 = sum of W2 rows of spiking layer-1 neurons ----
    float s0 = 0.f, s1 = 0.f, s2 = 0.f, s3 = 0.f;
#define ACC2(mask, qb)                            \
  {                                               \
    unsigned long long m = (mask);                \
    while (m) {                                   \
      int i = __builtin_ctzll(m) + (qb);          \
      m &= m - 1;                                 \
      float4 w = w2p[i * 64];                     \
      s0 += w.x;                                  \
      s1 += w.y;                                  \
      s2 += w.z;                                  \
      s3 += w.w;                                  \
    }                                             \
  }
    ACC2(m0, 0)
    ACC2(m1, 64)
    ACC2(m2, 128)
    ACC2(m3, 192)

    v20 = __fadd_rn(__fmul_rn(v20, decay), __fmul_rn(s0, omd));
    bool g0 = v20 >= 1.f;
    unsigned long long n0 = __ballot(g0);
    v20 = g0 ? 0.f : v20;
    v21 = __fadd_rn(__fmul_rn(v21, decay), __fmul_rn(s1, omd));
    bool g1 = v21 >= 1.f;
    unsigned long long n1 = __ballot(g1);
    v21 = g1 ? 0.f : v21;
    v22 = __fadd_rn(__fmul_rn(v22, decay), __fmul_rn(s2, omd));
    bool g2 = v22 >= 1.f;
    unsigned long long n2 = __ballot(g2);
    v22 = g2 ? 0.f : v22;
    v23 = __fadd_rn(__fmul_rn(v23, decay), __fmul_rn(s3, omd));
    bool g3 = v23 >= 1.f;
    unsigned long long n3 = __ballot(g3);
    v23 = g3 ? 0.f : v23;

    // ---- layer 3 (usually no layer-2 spikes: uniform skip) ----
    float z = 0.f;
    if (n0 | n1 | n2 | n3) {
#define ACC3(mask, qb)                            \
  {                                               \
    unsigned long long m = (mask);                \
    while (m) {                                   \
      int i = __builtin_ctzll(m) + (qb);          \
      m &= m - 1;                                 \
      z += W3[i * 64 + lane];                     \
    }                                             \
  }
      ACC3(n0, 0)
      ACC3(n1, 64)
      ACC3(n2, 128)
      ACC3(n3, 192)
    }
    v3 = __fadd_rn(__fmul_rn(v3, decay), __fmul_rn(z, omd));
    bool h = v3 >= 1.f;
    acc += h ? 1 : 0;
    v3 = h ? 0.f : v3;
  }
  out[(long)row * 64 + lane] = __fdiv_rn((float)acc, 100.f);
}

// ---------------------------------------------------------------------------
extern "C" void kernel_launch(void* const* d_in, const int* in_sizes, int n_in,
                              void* d_out, int out_size, void* d_ws,
                              size_t ws_size, hipStream_t stream) {
  const float* x = (const float*)d_in[0];     // [8192,256]
  const float* encW = (const float*)d_in[1];  // [256,256] (out,in)
  const float* encB = (const float*)d_in[2];  // [256]
  const float* W1 = (const float*)d_in[3];    // [256,256] (in,out) k-major
  const float* W2 = (const float*)d_in[4];    // [256,256]
  const float* W3 = (const float*)d_in[5];    // [256,64]
  float* out = (float*)d_out;                 // [8192,64]

  float* c = (float*)d_ws;                     // 8 MB
  float* rates = (float*)d_ws + 2097152;       // 8 MB
  float* W2p = (float*)d_ws + 4194304;         // 256 KB
  float* encWT = (float*)d_ws + 4194304 + 65536;  // 256 KB

  const float decay = (float)exp((double)(-0.05f));
  const float omd = 1.0f - decay;

  k_transpose256<<<256, 256, 0, stream>>>(encW, encWT);
  k_perm<<<256, 256, 0, stream>>>(W2, W2p);
  k_gemm64<0><<<512, 256, 0, stream>>>(x, encWT, encB, rates, omd);
  k_gemm64<1><<<512, 256, 0, stream>>>(rates, W1, encB, c, omd);
  k_sim<<<2048, 256, 0, stream>>>(c, W2p, W3, out, decay, omd);
}